// Round 1
// baseline (1388.225 us; speedup 1.0000x reference)
//
#include <hip/hip_runtime.h>
#include <math.h>

#define NNODE 50000
#define NEDGE 800000
#define FIN 128
#define EDIM 64
#define HC 256
#define NH 4
#define CC 64
#define SCAN_TILE 512

// ---------------- CSR build (dst -> incoming edge list) ----------------
__global__ void k_count(const int* __restrict__ dst, int* counts, int E) {
    int e = blockIdx.x * 256 + threadIdx.x;
    if (e < E) atomicAdd(&counts[dst[e]], 1);
}

__global__ void k_scan1(const int* __restrict__ counts, int* offs, int* tilesums, int N) {
    __shared__ int s[SCAN_TILE];
    int t = threadIdx.x;
    int i = blockIdx.x * SCAN_TILE + t;
    int v = (i < N) ? counts[i] : 0;
    s[t] = v;
    for (int off = 1; off < SCAN_TILE; off <<= 1) {
        __syncthreads();
        int x = (t >= off) ? s[t - off] : 0;
        __syncthreads();
        s[t] += x;
    }
    __syncthreads();
    if (i < N) offs[i] = s[t] - v;  // exclusive within tile
    if (t == SCAN_TILE - 1) tilesums[blockIdx.x] = s[t];
}

__global__ void k_scan2(int* tilesums, int nt) {
    if (threadIdx.x == 0) {
        int run = 0;
        for (int i = 0; i < nt; i++) { int v = tilesums[i]; tilesums[i] = run; run += v; }
    }
}

__global__ void k_scan3(int* offs, const int* __restrict__ tilesums, int N, int E) {
    int t = threadIdx.x;
    int i = blockIdx.x * SCAN_TILE + t;
    if (i < N) offs[i] += tilesums[blockIdx.x];
    if (i == 0) offs[N] = E;
}

__global__ void k_fill(const int* __restrict__ src, const int* __restrict__ dst,
                       const int* __restrict__ offs, int* cursor,
                       int* elist, int* slist, int E) {
    int e = blockIdx.x * 256 + threadIdx.x;
    if (e < E) {
        int d = dst[e];
        int pos = offs[d] + atomicAdd(&cursor[d], 1);
        elist[pos] = e;
        slist[pos] = src[e];
    }
}

// ---------------- fp32 tiled GEMM: C[M,256] = A[M,K] @ B[K,256] ----------------
__global__ __launch_bounds__(256) void k_gemm(const float* __restrict__ A,
                                              const float* __restrict__ B,
                                              float* __restrict__ Cm, int M, int K) {
    __shared__ float As[64][68];
    __shared__ float Bs[64][68];
    int tx = threadIdx.x & 15, ty = threadIdx.x >> 4;
    int row0 = blockIdx.x * 64, col0 = blockIdx.y * 64;
    float acc[4][4] = {};
    for (int k0 = 0; k0 < K; k0 += 64) {
        for (int i = 0; i < 4; i++) {
            int q = threadIdx.x + i * 256;       // float4 id 0..1023
            int m = q >> 4, k4 = (q & 15) << 2;
            float4 v = make_float4(0.f, 0.f, 0.f, 0.f);
            int gr = row0 + m;
            if (gr < M) v = *(const float4*)(A + (size_t)gr * K + k0 + k4);
            As[k4 + 0][m] = v.x; As[k4 + 1][m] = v.y;
            As[k4 + 2][m] = v.z; As[k4 + 3][m] = v.w;
            float4 wv = *(const float4*)(B + (size_t)(k0 + m) * HC + col0 + k4);
            *(float4*)&Bs[m][k4] = wv;
        }
        __syncthreads();
        for (int kk = 0; kk < 64; kk++) {
            float a[4], b[4];
            *(float4*)a = *(float4*)&As[kk][ty * 4];
            *(float4*)b = *(float4*)&Bs[kk][tx * 4];
            for (int i = 0; i < 4; i++)
                for (int j = 0; j < 4; j++) acc[i][j] += a[i] * b[j];
        }
        __syncthreads();
    }
    for (int i = 0; i < 4; i++) {
        int gr = row0 + ty * 4 + i;
        if (gr < M) *(float4*)(Cm + (size_t)gr * HC + col0 + tx * 4) = *(float4*)acc[i];
    }
}

// ---------------- per-node attention coefficients a_src, a_dst ----------------
__global__ void k_avec(const float* __restrict__ h, const float* __restrict__ att_s,
                       const float* __restrict__ att_d, float* asrc, float* adst, int N) {
    int wave = threadIdx.x >> 6, lane = threadIdx.x & 63;
    int n = blockIdx.x * 4 + wave;
    if (n >= N) return;
    for (int hh = 0; hh < 4; hh++) {
        float hv = h[(size_t)n * HC + hh * 64 + lane];
        float vs = hv * att_s[hh * 64 + lane];
        float vd = hv * att_d[hh * 64 + lane];
        for (int m = 32; m >= 1; m >>= 1) {
            vs += __shfl_xor(vs, m, 64);
            vd += __shfl_xor(vd, m, 64);
        }
        if (lane == 0) { asrc[n * 4 + hh] = vs; adst[n * 4 + hh] = vd; }
    }
}

// ---------------- we_att[d,h] = sum_c edgeW[d, h*64+c] * att_e[h,c] ----------------
__global__ void k_weatt(const float* __restrict__ edgeW, const float* __restrict__ att_e,
                        float* we) {
    int t = threadIdx.x;
    int d = t >> 2, hh = t & 3;
    float s = 0.f;
    for (int c = 0; c < 64; c++) s += edgeW[d * HC + hh * 64 + c] * att_e[hh * 64 + c];
    we[d * 4 + hh] = s;
}

// ---------------- elog[e,h] = edge_feat[e,:] . we_att[:,h] ----------------
__global__ void k_elog(const float* __restrict__ ef, const float* __restrict__ we,
                       float* __restrict__ elog, int E) {
    int wave = threadIdx.x >> 6, lane = threadIdx.x & 63;
    int e = blockIdx.x * 4 + wave;
    if (e >= E) return;
    float4 wv = ((const float4*)we)[lane];
    float x = ef[(size_t)e * EDIM + lane];
    float v0 = x * wv.x, v1 = x * wv.y, v2 = x * wv.z, v3 = x * wv.w;
    for (int m = 32; m >= 1; m >>= 1) {
        v0 += __shfl_xor(v0, m, 64);
        v1 += __shfl_xor(v1, m, 64);
        v2 += __shfl_xor(v2, m, 64);
        v3 += __shfl_xor(v3, m, 64);
    }
    if (lane == 0) ((float4*)elog)[e] = make_float4(v0, v1, v2, v3);
}

// ---------------- per-edge attention numerator p = exp(leakyrelu(.)) ----------------
__global__ void k_edgep(const int* __restrict__ src, const int* __restrict__ dst,
                        const float* __restrict__ elog, const float* __restrict__ asrc,
                        const float* __restrict__ adst, float* __restrict__ p, int E) {
    int e = blockIdx.x * 256 + threadIdx.x;
    if (e >= E) return;
    float4 el = ((const float4*)elog)[e];
    float4 as = ((const float4*)asrc)[src[e]];
    float4 ad = ((const float4*)adst)[dst[e]];
    float4 o;
    float l;
    l = as.x + ad.x + el.x; l = l > 0.f ? l : 0.2f * l; o.x = expf(l);
    l = as.y + ad.y + el.y; l = l > 0.f ? l : 0.2f * l; o.y = expf(l);
    l = as.z + ad.z + el.z; l = l > 0.f ? l : 0.2f * l; o.z = expf(l);
    l = as.w + ad.w + el.w; l = l > 0.f ? l : 0.2f * l; o.w = expf(l);
    ((float4*)p)[e] = o;
}

// ---------------- self-loop numerator pself (uses CSR segment sum of elog) ----------------
__global__ void k_pself(const float* __restrict__ elog, const int* __restrict__ offs,
                        const int* __restrict__ elist, const float* __restrict__ asrc,
                        const float* __restrict__ adst, float* __restrict__ pself, int N) {
    int wave = threadIdx.x >> 6, lane = threadIdx.x & 63;
    int n = blockIdx.x * 4 + wave;
    if (n >= N) return;
    int beg = offs[n], end = offs[n + 1];
    float s0 = 0.f, s1 = 0.f, s2 = 0.f, s3 = 0.f;
    for (int i = beg + lane; i < end; i += 64) {
        float4 el = ((const float4*)elog)[elist[i]];
        s0 += el.x; s1 += el.y; s2 += el.z; s3 += el.w;
    }
    for (int m = 32; m >= 1; m >>= 1) {
        s0 += __shfl_xor(s0, m, 64);
        s1 += __shfl_xor(s1, m, 64);
        s2 += __shfl_xor(s2, m, 64);
        s3 += __shfl_xor(s3, m, 64);
    }
    if (lane == 0) {
        float cnt = (float)(end - beg);
        if (cnt < 1.f) cnt = 1.f;
        float4 as = ((const float4*)asrc)[n];
        float4 ad = ((const float4*)adst)[n];
        float4 o;
        float l;
        l = as.x + ad.x + s0 / cnt; l = l > 0.f ? l : 0.2f * l; o.x = expf(l);
        l = as.y + ad.y + s1 / cnt; l = l > 0.f ? l : 0.2f * l; o.y = expf(l);
        l = as.z + ad.z + s2 / cnt; l = l > 0.f ? l : 0.2f * l; o.z = expf(l);
        l = as.w + ad.w + s3 / cnt; l = l > 0.f ? l : 0.2f * l; o.w = expf(l);
        ((float4*)pself)[n] = o;
    }
}

// ---------------- aggregation: block/node, wave/head, lane/channel ----------------
template <int LAYER>
__global__ __launch_bounds__(256) void k_aggr(const float* __restrict__ hfeat,
                                              const float* __restrict__ p,
                                              const float* __restrict__ pself,
                                              const int* __restrict__ offs,
                                              const int* __restrict__ elist,
                                              const int* __restrict__ slist,
                                              const float* __restrict__ bias,
                                              float* __restrict__ out, int N) {
    __shared__ float sm[4][64];
    int head = threadIdx.x >> 6, lane = threadIdx.x & 63;
    int n = blockIdx.x;
    int beg = offs[n], end = offs[n + 1];
    float ps = pself[n * 4 + head];
    float denom = ps;
    float acc = ps * hfeat[(size_t)n * HC + head * 64 + lane];
    for (int i = beg; i < end; i++) {
        int e = elist[i];
        int s = slist[i];
        float pw = p[e * 4 + head];
        denom += pw;
        acc += pw * hfeat[(size_t)s * HC + head * 64 + lane];
    }
    acc = acc / (denom + 1e-16f);
    if (LAYER == 1) {
        float v = acc + bias[head * 64 + lane];
        v = v > 0.f ? v : expf(v) - 1.0f;   // ELU fused
        out[(size_t)n * HC + head * 64 + lane] = v;
    } else {
        sm[head][lane] = acc;
        __syncthreads();
        if (head == 0) {
            float m = 0.25f * (sm[0][lane] + sm[1][lane] + sm[2][lane] + sm[3][lane]) + bias[lane];
            out[(size_t)n * CC + lane] = m;
        }
    }
}

extern "C" void kernel_launch(void* const* d_in, const int* in_sizes, int n_in,
                              void* d_out, int out_size, void* d_ws, size_t ws_size,
                              hipStream_t stream) {
    const float* x   = (const float*)d_in[0];
    const float* ef  = (const float*)d_in[1];
    const int*   ei  = (const int*)d_in[2];
    const float* W1  = (const float*)d_in[3];
    const float* as1 = (const float*)d_in[4];
    const float* ad1 = (const float*)d_in[5];
    const float* ae1 = (const float*)d_in[6];
    const float* b1  = (const float*)d_in[7];
    const float* eW1 = (const float*)d_in[8];
    const float* W2  = (const float*)d_in[9];
    const float* as2 = (const float*)d_in[10];
    const float* ad2 = (const float*)d_in[11];
    const float* ae2 = (const float*)d_in[12];
    const float* b2  = (const float*)d_in[13];
    const float* eW2 = (const float*)d_in[14];
    float* out = (float*)d_out;
    const int* srcp = ei;
    const int* dstp = ei + NEDGE;

    char* w = (char*)d_ws;
    auto alloc = [&](size_t bytes) -> char* {
        char* r = w;
        w += (bytes + 255) / 256 * 256;
        return r;
    };
    float* hbuf  = (float*)alloc((size_t)NNODE * HC * 4);
    float* x2buf = (float*)alloc((size_t)NNODE * HC * 4);
    float* elog  = (float*)alloc((size_t)NEDGE * 4 * 4);
    float* pbuf  = (float*)alloc((size_t)NEDGE * 4 * 4);
    float* asrc  = (float*)alloc((size_t)NNODE * 4 * 4);
    float* adst  = (float*)alloc((size_t)NNODE * 4 * 4);
    float* pself = (float*)alloc((size_t)NNODE * 4 * 4);
    float* webuf = (float*)alloc(64 * 4 * 4);
    int* counts  = (int*)alloc((size_t)NNODE * 4);
    int* offs    = (int*)alloc((size_t)(NNODE + 1) * 4);
    int* tiles   = (int*)alloc(1024 * 4);
    int* cursor  = (int*)alloc((size_t)NNODE * 4);
    int* elist   = (int*)alloc((size_t)NEDGE * 4);
    int* slist   = (int*)alloc((size_t)NEDGE * 4);

    hipMemsetAsync(counts, 0, (size_t)NNODE * 4, stream);
    hipMemsetAsync(cursor, 0, (size_t)NNODE * 4, stream);

    // CSR build (shared by both layers)
    k_count<<<(NEDGE + 255) / 256, 256, 0, stream>>>(dstp, counts, NEDGE);
    int nt = (NNODE + SCAN_TILE - 1) / SCAN_TILE;
    k_scan1<<<nt, SCAN_TILE, 0, stream>>>(counts, offs, tiles, NNODE);
    k_scan2<<<1, 64, 0, stream>>>(tiles, nt);
    k_scan3<<<nt, SCAN_TILE, 0, stream>>>(offs, tiles, NNODE, NEDGE);
    k_fill<<<(NEDGE + 255) / 256, 256, 0, stream>>>(srcp, dstp, offs, cursor, elist, slist, NEDGE);

    // ---- layer 1 ----
    k_gemm<<<dim3((NNODE + 63) / 64, 4), 256, 0, stream>>>(x, W1, hbuf, NNODE, FIN);
    k_avec<<<(NNODE + 3) / 4, 256, 0, stream>>>(hbuf, as1, ad1, asrc, adst, NNODE);
    k_weatt<<<1, 256, 0, stream>>>(eW1, ae1, webuf);
    k_elog<<<(NEDGE + 3) / 4, 256, 0, stream>>>(ef, webuf, elog, NEDGE);
    k_edgep<<<(NEDGE + 255) / 256, 256, 0, stream>>>(srcp, dstp, elog, asrc, adst, pbuf, NEDGE);
    k_pself<<<(NNODE + 3) / 4, 256, 0, stream>>>(elog, offs, elist, asrc, adst, pself, NNODE);
    k_aggr<1><<<NNODE, 256, 0, stream>>>(hbuf, pbuf, pself, offs, elist, slist, b1, x2buf, NNODE);

    // ---- layer 2 ----
    k_gemm<<<dim3((NNODE + 63) / 64, 4), 256, 0, stream>>>(x2buf, W2, hbuf, NNODE, HC);
    k_avec<<<(NNODE + 3) / 4, 256, 0, stream>>>(hbuf, as2, ad2, asrc, adst, NNODE);
    k_weatt<<<1, 256, 0, stream>>>(eW2, ae2, webuf);
    k_elog<<<(NEDGE + 3) / 4, 256, 0, stream>>>(ef, webuf, elog, NEDGE);
    k_edgep<<<(NEDGE + 255) / 256, 256, 0, stream>>>(srcp, dstp, elog, asrc, adst, pbuf, NEDGE);
    k_pself<<<(NNODE + 3) / 4, 256, 0, stream>>>(elog, offs, elist, asrc, adst, pself, NNODE);
    k_aggr<2><<<NNODE, 256, 0, stream>>>(hbuf, pbuf, pself, offs, elist, slist, b2, out, NNODE);
}

// Round 2
// 1102.710 us; speedup vs baseline: 1.2589x; 1.2589x over previous
//
#include <hip/hip_runtime.h>
#include <math.h>

#define NNODE 50000
#define NEDGE 800000
#define FIN 128
#define EDIM 64
#define HC 256
#define NH 4
#define CC 64
#define SCAN_TILE 512
#define EB 128   // edges per block in k_elog_both

// ---------------- CSR build (dst -> incoming edge list) ----------------
__global__ void k_count(const int* __restrict__ dst, int* counts, int E) {
    int e = blockIdx.x * 256 + threadIdx.x;
    if (e < E) atomicAdd(&counts[dst[e]], 1);
}

__global__ void k_scan1(const int* __restrict__ counts, int* offs, int* tilesums, int N) {
    __shared__ int s[SCAN_TILE];
    int t = threadIdx.x;
    int i = blockIdx.x * SCAN_TILE + t;
    int v = (i < N) ? counts[i] : 0;
    s[t] = v;
    for (int off = 1; off < SCAN_TILE; off <<= 1) {
        __syncthreads();
        int x = (t >= off) ? s[t - off] : 0;
        __syncthreads();
        s[t] += x;
    }
    __syncthreads();
    if (i < N) offs[i] = s[t] - v;  // exclusive within tile
    if (t == SCAN_TILE - 1) tilesums[blockIdx.x] = s[t];
}

__global__ void k_scan2(int* tilesums, int nt) {
    if (threadIdx.x == 0) {
        int run = 0;
        for (int i = 0; i < nt; i++) { int v = tilesums[i]; tilesums[i] = run; run += v; }
    }
}

__global__ void k_scan3(int* offs, const int* __restrict__ tilesums, int N, int E) {
    int t = threadIdx.x;
    int i = blockIdx.x * SCAN_TILE + t;
    if (i < N) offs[i] += tilesums[blockIdx.x];
    if (i == 0) offs[N] = E;
}

__global__ void k_fill(const int* __restrict__ src, const int* __restrict__ dst,
                       const int* __restrict__ offs, int* cursor,
                       int* elist, int* slist, int E) {
    int e = blockIdx.x * 256 + threadIdx.x;
    if (e < E) {
        int d = dst[e];
        int pos = offs[d] + atomicAdd(&cursor[d], 1);
        elist[pos] = e;
        slist[pos] = src[e];
    }
}

// ---------------- fp32 tiled GEMM: C[M,256] = A[M,K] @ B[K,256] ----------------
__global__ __launch_bounds__(256) void k_gemm(const float* __restrict__ A,
                                              const float* __restrict__ B,
                                              float* __restrict__ Cm, int M, int K) {
    __shared__ float As[64][68];
    __shared__ float Bs[64][68];
    int tx = threadIdx.x & 15, ty = threadIdx.x >> 4;
    int row0 = blockIdx.x * 64, col0 = blockIdx.y * 64;
    float acc[4][4] = {};
    for (int k0 = 0; k0 < K; k0 += 64) {
        for (int i = 0; i < 4; i++) {
            int q = threadIdx.x + i * 256;       // float4 id 0..1023
            int m = q >> 4, k4 = (q & 15) << 2;
            float4 v = make_float4(0.f, 0.f, 0.f, 0.f);
            int gr = row0 + m;
            if (gr < M) v = *(const float4*)(A + (size_t)gr * K + k0 + k4);
            As[k4 + 0][m] = v.x; As[k4 + 1][m] = v.y;
            As[k4 + 2][m] = v.z; As[k4 + 3][m] = v.w;
            float4 wv = *(const float4*)(B + (size_t)(k0 + m) * HC + col0 + k4);
            *(float4*)&Bs[m][k4] = wv;
        }
        __syncthreads();
        for (int kk = 0; kk < 64; kk++) {
            float a[4], b[4];
            *(float4*)a = *(float4*)&As[kk][ty * 4];
            *(float4*)b = *(float4*)&Bs[kk][tx * 4];
            for (int i = 0; i < 4; i++)
                for (int j = 0; j < 4; j++) acc[i][j] += a[i] * b[j];
        }
        __syncthreads();
    }
    for (int i = 0; i < 4; i++) {
        int gr = row0 + ty * 4 + i;
        if (gr < M) *(float4*)(Cm + (size_t)gr * HC + col0 + tx * 4) = *(float4*)acc[i];
    }
}

// ---------------- per-node attention coefficients a_src, a_dst ----------------
__global__ void k_avec(const float* __restrict__ h, const float* __restrict__ att_s,
                       const float* __restrict__ att_d, float* asrc, float* adst, int N) {
    int wave = threadIdx.x >> 6, lane = threadIdx.x & 63;
    int n = blockIdx.x * 4 + wave;
    if (n >= N) return;
    for (int hh = 0; hh < 4; hh++) {
        float hv = h[(size_t)n * HC + hh * 64 + lane];
        float vs = hv * att_s[hh * 64 + lane];
        float vd = hv * att_d[hh * 64 + lane];
        for (int m = 32; m >= 1; m >>= 1) {
            vs += __shfl_xor(vs, m, 64);
            vd += __shfl_xor(vd, m, 64);
        }
        if (lane == 0) { asrc[n * 4 + hh] = vs; adst[n * 4 + hh] = vd; }
    }
}

// ---------------- we_att[d,h] = sum_c edgeW[d, h*64+c] * att_e[h,c] ----------------
__global__ void k_weatt(const float* __restrict__ edgeW, const float* __restrict__ att_e,
                        float* we) {
    int t = threadIdx.x;
    int d = t >> 2, hh = t & 3;
    float s = 0.f;
    for (int c = 0; c < 64; c++) s += edgeW[d * HC + hh * 64 + c] * att_e[hh * 64 + c];
    we[d * 4 + hh] = s;
}

// ---------------- elog{1,2}[e,h] = edge_feat[e,:] . we{1,2}[:,h]  (both layers, one ef pass) ----
__global__ __launch_bounds__(128) void k_elog_both(const float* __restrict__ ef,
                                                   const float* __restrict__ we1,
                                                   const float* __restrict__ we2,
                                                   float* __restrict__ elog1,
                                                   float* __restrict__ elog2, int E) {
    __shared__ float sEf[EB][65];   // 65-pad: compute reads (lane+c)%32 -> 2-way (free)
    int t = threadIdx.x;
    int e0 = blockIdx.x * EB;
    // stage 128 edges x 64 dims, coalesced float4
    for (int i = 0; i < 16; i++) {
        int q = t + i * 128;
        int le = q >> 4, c4 = (q & 15) << 2;
        int ge = e0 + le;
        float4 v = make_float4(0.f, 0.f, 0.f, 0.f);
        if (ge < E) v = *(const float4*)(ef + (size_t)ge * EDIM + c4);
        sEf[le][c4 + 0] = v.x; sEf[le][c4 + 1] = v.y;
        sEf[le][c4 + 2] = v.z; sEf[le][c4 + 3] = v.w;
    }
    __syncthreads();
    float a1[4] = {}, a2[4] = {};
#pragma unroll 8
    for (int c = 0; c < 64; c++) {
        float v = sEf[t][c];
        float4 w1 = *(const float4*)(we1 + c * 4);   // wave-uniform -> s_load_dwordx4
        float4 w2 = *(const float4*)(we2 + c * 4);
        a1[0] += v * w1.x; a1[1] += v * w1.y; a1[2] += v * w1.z; a1[3] += v * w1.w;
        a2[0] += v * w2.x; a2[1] += v * w2.y; a2[2] += v * w2.z; a2[3] += v * w2.w;
    }
    int e = e0 + t;
    if (e < E) {
        ((float4*)elog1)[e] = make_float4(a1[0], a1[1], a1[2], a1[3]);
        ((float4*)elog2)[e] = make_float4(a2[0], a2[1], a2[2], a2[3]);
    }
}

// ---------------- per-edge attention numerator p = exp(leakyrelu(.)) ----------------
__global__ void k_edgep(const int* __restrict__ src, const int* __restrict__ dst,
                        const float* __restrict__ elog, const float* __restrict__ asrc,
                        const float* __restrict__ adst, float* __restrict__ p, int E) {
    int e = blockIdx.x * 256 + threadIdx.x;
    if (e >= E) return;
    float4 el = ((const float4*)elog)[e];
    float4 as = ((const float4*)asrc)[src[e]];
    float4 ad = ((const float4*)adst)[dst[e]];
    float4 o;
    float l;
    l = as.x + ad.x + el.x; l = l > 0.f ? l : 0.2f * l; o.x = expf(l);
    l = as.y + ad.y + el.y; l = l > 0.f ? l : 0.2f * l; o.y = expf(l);
    l = as.z + ad.z + el.z; l = l > 0.f ? l : 0.2f * l; o.z = expf(l);
    l = as.w + ad.w + el.w; l = l > 0.f ? l : 0.2f * l; o.w = expf(l);
    ((float4*)p)[e] = o;
}

// ---------------- self-loop numerator pself (uses CSR segment sum of elog) ----------------
__global__ void k_pself(const float* __restrict__ elog, const int* __restrict__ offs,
                        const int* __restrict__ elist, const float* __restrict__ asrc,
                        const float* __restrict__ adst, float* __restrict__ pself, int N) {
    int wave = threadIdx.x >> 6, lane = threadIdx.x & 63;
    int n = blockIdx.x * 4 + wave;
    if (n >= N) return;
    int beg = offs[n], end = offs[n + 1];
    float s0 = 0.f, s1 = 0.f, s2 = 0.f, s3 = 0.f;
    for (int i = beg + lane; i < end; i += 64) {
        float4 el = ((const float4*)elog)[elist[i]];
        s0 += el.x; s1 += el.y; s2 += el.z; s3 += el.w;
    }
    for (int m = 32; m >= 1; m >>= 1) {
        s0 += __shfl_xor(s0, m, 64);
        s1 += __shfl_xor(s1, m, 64);
        s2 += __shfl_xor(s2, m, 64);
        s3 += __shfl_xor(s3, m, 64);
    }
    if (lane == 0) {
        float cnt = (float)(end - beg);
        if (cnt < 1.f) cnt = 1.f;
        float4 as = ((const float4*)asrc)[n];
        float4 ad = ((const float4*)adst)[n];
        float4 o;
        float l;
        l = as.x + ad.x + s0 / cnt; l = l > 0.f ? l : 0.2f * l; o.x = expf(l);
        l = as.y + ad.y + s1 / cnt; l = l > 0.f ? l : 0.2f * l; o.y = expf(l);
        l = as.z + ad.z + s2 / cnt; l = l > 0.f ? l : 0.2f * l; o.z = expf(l);
        l = as.w + ad.w + s3 / cnt; l = l > 0.f ? l : 0.2f * l; o.w = expf(l);
        ((float4*)pself)[n] = o;
    }
}

// ---------------- aggregation: block/node, wave/head, lane/channel ----------------
template <int LAYER>
__global__ __launch_bounds__(256) void k_aggr(const float* __restrict__ hfeat,
                                              const float* __restrict__ p,
                                              const float* __restrict__ pself,
                                              const int* __restrict__ offs,
                                              const int* __restrict__ elist,
                                              const int* __restrict__ slist,
                                              const float* __restrict__ bias,
                                              float* __restrict__ out, int N) {
    __shared__ float sm[4][64];
    int head = threadIdx.x >> 6, lane = threadIdx.x & 63;
    int n = blockIdx.x;
    int beg = offs[n], end = offs[n + 1];
    float ps = pself[n * 4 + head];
    float denom = ps;
    float acc = ps * hfeat[(size_t)n * HC + head * 64 + lane];
    for (int i = beg; i < end; i++) {
        int e = elist[i];
        int s = slist[i];
        float pw = p[e * 4 + head];
        denom += pw;
        acc += pw * hfeat[(size_t)s * HC + head * 64 + lane];
    }
    acc = acc / (denom + 1e-16f);
    if (LAYER == 1) {
        float v = acc + bias[head * 64 + lane];
        v = v > 0.f ? v : expf(v) - 1.0f;   // ELU fused
        out[(size_t)n * HC + head * 64 + lane] = v;
    } else {
        sm[head][lane] = acc;
        __syncthreads();
        if (head == 0) {
            float m = 0.25f * (sm[0][lane] + sm[1][lane] + sm[2][lane] + sm[3][lane]) + bias[lane];
            out[(size_t)n * CC + lane] = m;
        }
    }
}

extern "C" void kernel_launch(void* const* d_in, const int* in_sizes, int n_in,
                              void* d_out, int out_size, void* d_ws, size_t ws_size,
                              hipStream_t stream) {
    const float* x   = (const float*)d_in[0];
    const float* ef  = (const float*)d_in[1];
    const int*   ei  = (const int*)d_in[2];
    const float* W1  = (const float*)d_in[3];
    const float* as1 = (const float*)d_in[4];
    const float* ad1 = (const float*)d_in[5];
    const float* ae1 = (const float*)d_in[6];
    const float* b1  = (const float*)d_in[7];
    const float* eW1 = (const float*)d_in[8];
    const float* W2  = (const float*)d_in[9];
    const float* as2 = (const float*)d_in[10];
    const float* ad2 = (const float*)d_in[11];
    const float* ae2 = (const float*)d_in[12];
    const float* b2  = (const float*)d_in[13];
    const float* eW2 = (const float*)d_in[14];
    float* out = (float*)d_out;
    const int* srcp = ei;
    const int* dstp = ei + NEDGE;

    char* w = (char*)d_ws;
    auto alloc = [&](size_t bytes) -> char* {
        char* r = w;
        w += (bytes + 255) / 256 * 256;
        return r;
    };
    float* hbuf  = (float*)alloc((size_t)NNODE * HC * 4);
    float* x2buf = (float*)alloc((size_t)NNODE * HC * 4);
    float* elog1 = (float*)alloc((size_t)NEDGE * 4 * 4);
    float* elog2 = (float*)alloc((size_t)NEDGE * 4 * 4);
    float* pbuf  = (float*)alloc((size_t)NEDGE * 4 * 4);
    float* asrc  = (float*)alloc((size_t)NNODE * 4 * 4);
    float* adst  = (float*)alloc((size_t)NNODE * 4 * 4);
    float* pself = (float*)alloc((size_t)NNODE * 4 * 4);
    float* webuf1 = (float*)alloc(64 * 4 * 4);
    float* webuf2 = (float*)alloc(64 * 4 * 4);
    int* counts  = (int*)alloc((size_t)NNODE * 4);
    int* offs    = (int*)alloc((size_t)(NNODE + 1) * 4);
    int* tiles   = (int*)alloc(1024 * 4);
    int* cursor  = (int*)alloc((size_t)NNODE * 4);
    int* elist   = (int*)alloc((size_t)NEDGE * 4);
    int* slist   = (int*)alloc((size_t)NEDGE * 4);

    hipMemsetAsync(counts, 0, (size_t)NNODE * 4, stream);
    hipMemsetAsync(cursor, 0, (size_t)NNODE * 4, stream);

    // CSR build (shared by both layers)
    k_count<<<(NEDGE + 255) / 256, 256, 0, stream>>>(dstp, counts, NEDGE);
    int nt = (NNODE + SCAN_TILE - 1) / SCAN_TILE;
    k_scan1<<<nt, SCAN_TILE, 0, stream>>>(counts, offs, tiles, NNODE);
    k_scan2<<<1, 64, 0, stream>>>(tiles, nt);
    k_scan3<<<nt, SCAN_TILE, 0, stream>>>(offs, tiles, NNODE, NEDGE);
    k_fill<<<(NEDGE + 255) / 256, 256, 0, stream>>>(srcp, dstp, offs, cursor, elist, slist, NEDGE);

    // edge logits for BOTH layers in one pass over ef (205 MB read once)
    k_weatt<<<1, 256, 0, stream>>>(eW1, ae1, webuf1);
    k_weatt<<<1, 256, 0, stream>>>(eW2, ae2, webuf2);
    k_elog_both<<<(NEDGE + EB - 1) / EB, EB, 0, stream>>>(ef, webuf1, webuf2, elog1, elog2, NEDGE);

    // ---- layer 1 ----
    k_gemm<<<dim3((NNODE + 63) / 64, 4), 256, 0, stream>>>(x, W1, hbuf, NNODE, FIN);
    k_avec<<<(NNODE + 3) / 4, 256, 0, stream>>>(hbuf, as1, ad1, asrc, adst, NNODE);
    k_edgep<<<(NEDGE + 255) / 256, 256, 0, stream>>>(srcp, dstp, elog1, asrc, adst, pbuf, NEDGE);
    k_pself<<<(NNODE + 3) / 4, 256, 0, stream>>>(elog1, offs, elist, asrc, adst, pself, NNODE);
    k_aggr<1><<<NNODE, 256, 0, stream>>>(hbuf, pbuf, pself, offs, elist, slist, b1, x2buf, NNODE);

    // ---- layer 2 ----
    k_gemm<<<dim3((NNODE + 63) / 64, 4), 256, 0, stream>>>(x2buf, W2, hbuf, NNODE, HC);
    k_avec<<<(NNODE + 3) / 4, 256, 0, stream>>>(hbuf, as2, ad2, asrc, adst, NNODE);
    k_edgep<<<(NEDGE + 255) / 256, 256, 0, stream>>>(srcp, dstp, elog2, asrc, adst, pbuf, NEDGE);
    k_pself<<<(NNODE + 3) / 4, 256, 0, stream>>>(elog2, offs, elist, asrc, adst, pself, NNODE);
    k_aggr<2><<<NNODE, 256, 0, stream>>>(hbuf, pbuf, pself, offs, elist, slist, b2, out, NNODE);
}

// Round 3
// 979.057 us; speedup vs baseline: 1.4179x; 1.1263x over previous
//
#include <hip/hip_runtime.h>
#include <math.h>

#define NNODE 50000
#define NEDGE 800000
#define FIN 128
#define EDIM 64
#define HC 256
#define NH 4
#define CC 64
#define SCAN_TILE 512
#define EB 128   // edges per block in k_elog_both

// ---------------- CSR build (dst -> incoming edge list) ----------------
__global__ void k_count(const int* __restrict__ dst, int* counts, int E) {
    int e = blockIdx.x * 256 + threadIdx.x;
    if (e < E) atomicAdd(&counts[dst[e]], 1);
}

__global__ void k_scan1(const int* __restrict__ counts, int* offs, int* tilesums, int N) {
    __shared__ int s[SCAN_TILE];
    int t = threadIdx.x;
    int i = blockIdx.x * SCAN_TILE + t;
    int v = (i < N) ? counts[i] : 0;
    s[t] = v;
    for (int off = 1; off < SCAN_TILE; off <<= 1) {
        __syncthreads();
        int x = (t >= off) ? s[t - off] : 0;
        __syncthreads();
        s[t] += x;
    }
    __syncthreads();
    if (i < N) offs[i] = s[t] - v;  // exclusive within tile
    if (t == SCAN_TILE - 1) tilesums[blockIdx.x] = s[t];
}

__global__ void k_scan2(int* tilesums, int nt) {
    if (threadIdx.x == 0) {
        int run = 0;
        for (int i = 0; i < nt; i++) { int v = tilesums[i]; tilesums[i] = run; run += v; }
    }
}

__global__ void k_scan3(int* offs, const int* __restrict__ tilesums, int N, int E) {
    int t = threadIdx.x;
    int i = blockIdx.x * SCAN_TILE + t;
    if (i < N) offs[i] += tilesums[blockIdx.x];
    if (i == 0) offs[N] = E;
}

__global__ void k_fill(const int* __restrict__ src, const int* __restrict__ dst,
                       const int* __restrict__ offs, int* cursor,
                       int* elist, int* slist, int* dlist, int E) {
    int e = blockIdx.x * 256 + threadIdx.x;
    if (e < E) {
        int d = dst[e];
        int pos = offs[d] + atomicAdd(&cursor[d], 1);
        elist[pos] = e;
        slist[pos] = src[e];
        dlist[pos] = d;
    }
}

// ---------------- fp32 tiled GEMM: C[M,256] = A[M,K] @ B[K,256] ----------------
__global__ __launch_bounds__(256) void k_gemm(const float* __restrict__ A,
                                              const float* __restrict__ B,
                                              float* __restrict__ Cm, int M, int K) {
    __shared__ float As[64][68];
    __shared__ float Bs[64][68];
    int tx = threadIdx.x & 15, ty = threadIdx.x >> 4;
    int row0 = blockIdx.x * 64, col0 = blockIdx.y * 64;
    float acc[4][4] = {};
    for (int k0 = 0; k0 < K; k0 += 64) {
        for (int i = 0; i < 4; i++) {
            int q = threadIdx.x + i * 256;       // float4 id 0..1023
            int m = q >> 4, k4 = (q & 15) << 2;
            float4 v = make_float4(0.f, 0.f, 0.f, 0.f);
            int gr = row0 + m;
            if (gr < M) v = *(const float4*)(A + (size_t)gr * K + k0 + k4);
            As[k4 + 0][m] = v.x; As[k4 + 1][m] = v.y;
            As[k4 + 2][m] = v.z; As[k4 + 3][m] = v.w;
            float4 wv = *(const float4*)(B + (size_t)(k0 + m) * HC + col0 + k4);
            *(float4*)&Bs[m][k4] = wv;
        }
        __syncthreads();
        for (int kk = 0; kk < 64; kk++) {
            float a[4], b[4];
            *(float4*)a = *(float4*)&As[kk][ty * 4];
            *(float4*)b = *(float4*)&Bs[kk][tx * 4];
            for (int i = 0; i < 4; i++)
                for (int j = 0; j < 4; j++) acc[i][j] += a[i] * b[j];
        }
        __syncthreads();
    }
    for (int i = 0; i < 4; i++) {
        int gr = row0 + ty * 4 + i;
        if (gr < M) *(float4*)(Cm + (size_t)gr * HC + col0 + tx * 4) = *(float4*)acc[i];
    }
}

// ---------------- per-node attention coefficients a_src, a_dst ----------------
__global__ void k_avec(const float* __restrict__ h, const float* __restrict__ att_s,
                       const float* __restrict__ att_d, float* asrc, float* adst, int N) {
    int wave = threadIdx.x >> 6, lane = threadIdx.x & 63;
    int n = blockIdx.x * 4 + wave;
    if (n >= N) return;
    for (int hh = 0; hh < 4; hh++) {
        float hv = h[(size_t)n * HC + hh * 64 + lane];
        float vs = hv * att_s[hh * 64 + lane];
        float vd = hv * att_d[hh * 64 + lane];
        for (int m = 32; m >= 1; m >>= 1) {
            vs += __shfl_xor(vs, m, 64);
            vd += __shfl_xor(vd, m, 64);
        }
        if (lane == 0) { asrc[n * 4 + hh] = vs; adst[n * 4 + hh] = vd; }
    }
}

// ---------------- we_att[d,h] = sum_c edgeW[d, h*64+c] * att_e[h,c] ----------------
__global__ void k_weatt(const float* __restrict__ edgeW, const float* __restrict__ att_e,
                        float* we) {
    int t = threadIdx.x;
    int d = t >> 2, hh = t & 3;
    float s = 0.f;
    for (int c = 0; c < 64; c++) s += edgeW[d * HC + hh * 64 + c] * att_e[hh * 64 + c];
    we[d * 4 + hh] = s;
}

// ---------------- elog{1,2}[e,h] = edge_feat[e,:] . we{1,2}[:,h]  (both layers, one ef pass) ----
__global__ __launch_bounds__(128) void k_elog_both(const float* __restrict__ ef,
                                                   const float* __restrict__ we1,
                                                   const float* __restrict__ we2,
                                                   float* __restrict__ elog1,
                                                   float* __restrict__ elog2, int E) {
    __shared__ float sEf[EB][65];
    int t = threadIdx.x;
    int e0 = blockIdx.x * EB;
    for (int i = 0; i < 16; i++) {
        int q = t + i * 128;
        int le = q >> 4, c4 = (q & 15) << 2;
        int ge = e0 + le;
        float4 v = make_float4(0.f, 0.f, 0.f, 0.f);
        if (ge < E) v = *(const float4*)(ef + (size_t)ge * EDIM + c4);
        sEf[le][c4 + 0] = v.x; sEf[le][c4 + 1] = v.y;
        sEf[le][c4 + 2] = v.z; sEf[le][c4 + 3] = v.w;
    }
    __syncthreads();
    float a1[4] = {}, a2[4] = {};
#pragma unroll 8
    for (int c = 0; c < 64; c++) {
        float v = sEf[t][c];
        float4 w1 = *(const float4*)(we1 + c * 4);
        float4 w2 = *(const float4*)(we2 + c * 4);
        a1[0] += v * w1.x; a1[1] += v * w1.y; a1[2] += v * w1.z; a1[3] += v * w1.w;
        a2[0] += v * w2.x; a2[1] += v * w2.y; a2[2] += v * w2.z; a2[3] += v * w2.w;
    }
    int e = e0 + t;
    if (e < E) {
        ((float4*)elog1)[e] = make_float4(a1[0], a1[1], a1[2], a1[3]);
        ((float4*)elog2)[e] = make_float4(a2[0], a2[1], a2[2], a2[3]);
    }
}

// ---------------- per-edge attention numerator in CSR order ----------------
__global__ void k_edgep(const int* __restrict__ slist, const int* __restrict__ dlist,
                        const int* __restrict__ elist,
                        const float* __restrict__ elog, const float* __restrict__ asrc,
                        const float* __restrict__ adst, float* __restrict__ pcsr, int E) {
    int i = blockIdx.x * 256 + threadIdx.x;
    if (i >= E) return;
    float4 el = ((const float4*)elog)[elist[i]];
    float4 as = ((const float4*)asrc)[slist[i]];
    float4 ad = ((const float4*)adst)[dlist[i]];
    float4 o;
    float l;
    l = as.x + ad.x + el.x; l = l > 0.f ? l : 0.2f * l; o.x = expf(l);
    l = as.y + ad.y + el.y; l = l > 0.f ? l : 0.2f * l; o.y = expf(l);
    l = as.z + ad.z + el.z; l = l > 0.f ? l : 0.2f * l; o.z = expf(l);
    l = as.w + ad.w + el.w; l = l > 0.f ? l : 0.2f * l; o.w = expf(l);
    ((float4*)pcsr)[i] = o;
}

// ---------------- self-loop numerator pself (uses CSR segment sum of elog) ----------------
__global__ void k_pself(const float* __restrict__ elog, const int* __restrict__ offs,
                        const int* __restrict__ elist, const float* __restrict__ asrc,
                        const float* __restrict__ adst, float* __restrict__ pself, int N) {
    int wave = threadIdx.x >> 6, lane = threadIdx.x & 63;
    int n = blockIdx.x * 4 + wave;
    if (n >= N) return;
    int beg = offs[n], end = offs[n + 1];
    float s0 = 0.f, s1 = 0.f, s2 = 0.f, s3 = 0.f;
    for (int i = beg + lane; i < end; i += 64) {
        float4 el = ((const float4*)elog)[elist[i]];
        s0 += el.x; s1 += el.y; s2 += el.z; s3 += el.w;
    }
    for (int m = 32; m >= 1; m >>= 1) {
        s0 += __shfl_xor(s0, m, 64);
        s1 += __shfl_xor(s1, m, 64);
        s2 += __shfl_xor(s2, m, 64);
        s3 += __shfl_xor(s3, m, 64);
    }
    if (lane == 0) {
        float cnt = (float)(end - beg);
        if (cnt < 1.f) cnt = 1.f;
        float4 as = ((const float4*)asrc)[n];
        float4 ad = ((const float4*)adst)[n];
        float4 o;
        float l;
        l = as.x + ad.x + s0 / cnt; l = l > 0.f ? l : 0.2f * l; o.x = expf(l);
        l = as.y + ad.y + s1 / cnt; l = l > 0.f ? l : 0.2f * l; o.y = expf(l);
        l = as.z + ad.z + s2 / cnt; l = l > 0.f ? l : 0.2f * l; o.z = expf(l);
        l = as.w + ad.w + s3 / cnt; l = l > 0.f ? l : 0.2f * l; o.w = expf(l);
        ((float4*)pself)[n] = o;
    }
}

// ---------------- aggregation: wave/node, lane/(4 flat channels) ----------------
template <int LAYER>
__global__ __launch_bounds__(256) void k_aggr(const float* __restrict__ hfeat,
                                              const float* __restrict__ pcsr,
                                              const float* __restrict__ pself,
                                              const int* __restrict__ offs,
                                              const int* __restrict__ slist,
                                              const float* __restrict__ bias,
                                              float* __restrict__ out, int N) {
    int wave = threadIdx.x >> 6, lane = threadIdx.x & 63;
    int n = blockIdx.x * 4 + wave;
    if (n >= N) return;
    int head = lane >> 4;
    const float4* hf = (const float4*)hfeat;
    const float4* pc = (const float4*)pcsr;
    int beg = offs[n], end = offs[n + 1];

    float4 ps4 = ((const float4*)pself)[n];
    float ps = head == 0 ? ps4.x : head == 1 ? ps4.y : head == 2 ? ps4.z : ps4.w;
    float4 hv = hf[(size_t)n * 64 + lane];
    float denom = ps;
    float ax = ps * hv.x, ay = ps * hv.y, az = ps * hv.z, aw = ps * hv.w;

    int i = beg;
    for (; i + 4 <= end; i += 4) {
        int s0 = slist[i], s1 = slist[i + 1], s2 = slist[i + 2], s3 = slist[i + 3];
        float4 p0 = pc[i], p1 = pc[i + 1], p2 = pc[i + 2], p3 = pc[i + 3];
        float4 h0 = hf[(size_t)s0 * 64 + lane];
        float4 h1 = hf[(size_t)s1 * 64 + lane];
        float4 h2 = hf[(size_t)s2 * 64 + lane];
        float4 h3 = hf[(size_t)s3 * 64 + lane];
        float w0 = head == 0 ? p0.x : head == 1 ? p0.y : head == 2 ? p0.z : p0.w;
        float w1 = head == 0 ? p1.x : head == 1 ? p1.y : head == 2 ? p1.z : p1.w;
        float w2 = head == 0 ? p2.x : head == 1 ? p2.y : head == 2 ? p2.z : p2.w;
        float w3 = head == 0 ? p3.x : head == 1 ? p3.y : head == 2 ? p3.z : p3.w;
        denom += w0 + w1 + w2 + w3;
        ax += w0 * h0.x + w1 * h1.x + w2 * h2.x + w3 * h3.x;
        ay += w0 * h0.y + w1 * h1.y + w2 * h2.y + w3 * h3.y;
        az += w0 * h0.z + w1 * h1.z + w2 * h2.z + w3 * h3.z;
        aw += w0 * h0.w + w1 * h1.w + w2 * h2.w + w3 * h3.w;
    }
    for (; i < end; i++) {
        int s0 = slist[i];
        float4 p0 = pc[i];
        float4 h0 = hf[(size_t)s0 * 64 + lane];
        float w0 = head == 0 ? p0.x : head == 1 ? p0.y : head == 2 ? p0.z : p0.w;
        denom += w0;
        ax += w0 * h0.x; ay += w0 * h0.y; az += w0 * h0.z; aw += w0 * h0.w;
    }
    float inv = 1.0f / (denom + 1e-16f);
    ax *= inv; ay *= inv; az *= inv; aw *= inv;

    if (LAYER == 1) {
        float4 bv = ((const float4*)bias)[lane];
        float4 o;
        float v;
        v = ax + bv.x; o.x = v > 0.f ? v : expf(v) - 1.0f;
        v = ay + bv.y; o.y = v > 0.f ? v : expf(v) - 1.0f;
        v = az + bv.z; o.z = v > 0.f ? v : expf(v) - 1.0f;
        v = aw + bv.w; o.w = v > 0.f ? v : expf(v) - 1.0f;
        ((float4*)(out + (size_t)n * HC))[lane] = o;
    } else {
        // mean over heads: reduce lanes {l, l^16, l^32, l^48}
        ax += __shfl_xor(ax, 16, 64); ax += __shfl_xor(ax, 32, 64);
        ay += __shfl_xor(ay, 16, 64); ay += __shfl_xor(ay, 32, 64);
        az += __shfl_xor(az, 16, 64); az += __shfl_xor(az, 32, 64);
        aw += __shfl_xor(aw, 16, 64); aw += __shfl_xor(aw, 32, 64);
        if (lane < 16) {
            float4 bv = ((const float4*)bias)[lane];
            float4 o;
            o.x = 0.25f * ax + bv.x;
            o.y = 0.25f * ay + bv.y;
            o.z = 0.25f * az + bv.z;
            o.w = 0.25f * aw + bv.w;
            ((float4*)(out + (size_t)n * CC))[lane] = o;
        }
    }
}

extern "C" void kernel_launch(void* const* d_in, const int* in_sizes, int n_in,
                              void* d_out, int out_size, void* d_ws, size_t ws_size,
                              hipStream_t stream) {
    const float* x   = (const float*)d_in[0];
    const float* ef  = (const float*)d_in[1];
    const int*   ei  = (const int*)d_in[2];
    const float* W1  = (const float*)d_in[3];
    const float* as1 = (const float*)d_in[4];
    const float* ad1 = (const float*)d_in[5];
    const float* ae1 = (const float*)d_in[6];
    const float* b1  = (const float*)d_in[7];
    const float* eW1 = (const float*)d_in[8];
    const float* W2  = (const float*)d_in[9];
    const float* as2 = (const float*)d_in[10];
    const float* ad2 = (const float*)d_in[11];
    const float* ae2 = (const float*)d_in[12];
    const float* b2  = (const float*)d_in[13];
    const float* eW2 = (const float*)d_in[14];
    float* out = (float*)d_out;
    const int* srcp = ei;
    const int* dstp = ei + NEDGE;

    char* w = (char*)d_ws;
    auto alloc = [&](size_t bytes) -> char* {
        char* r = w;
        w += (bytes + 255) / 256 * 256;
        return r;
    };
    float* hbuf  = (float*)alloc((size_t)NNODE * HC * 4);
    float* x2buf = (float*)alloc((size_t)NNODE * HC * 4);
    float* elog1 = (float*)alloc((size_t)NEDGE * 4 * 4);
    float* elog2 = (float*)alloc((size_t)NEDGE * 4 * 4);
    float* pbuf  = (float*)alloc((size_t)NEDGE * 4 * 4);
    float* asrc  = (float*)alloc((size_t)NNODE * 4 * 4);
    float* adst  = (float*)alloc((size_t)NNODE * 4 * 4);
    float* pself = (float*)alloc((size_t)NNODE * 4 * 4);
    float* webuf1 = (float*)alloc(64 * 4 * 4);
    float* webuf2 = (float*)alloc(64 * 4 * 4);
    int* counts  = (int*)alloc((size_t)NNODE * 4);
    int* offs    = (int*)alloc((size_t)(NNODE + 1) * 4);
    int* tiles   = (int*)alloc(1024 * 4);
    int* cursor  = (int*)alloc((size_t)NNODE * 4);
    int* elist   = (int*)alloc((size_t)NEDGE * 4);
    int* slist   = (int*)alloc((size_t)NEDGE * 4);
    int* dlist   = (int*)alloc((size_t)NEDGE * 4);

    hipMemsetAsync(counts, 0, (size_t)NNODE * 4, stream);
    hipMemsetAsync(cursor, 0, (size_t)NNODE * 4, stream);

    // CSR build (shared by both layers)
    k_count<<<(NEDGE + 255) / 256, 256, 0, stream>>>(dstp, counts, NEDGE);
    int nt = (NNODE + SCAN_TILE - 1) / SCAN_TILE;
    k_scan1<<<nt, SCAN_TILE, 0, stream>>>(counts, offs, tiles, NNODE);
    k_scan2<<<1, 64, 0, stream>>>(tiles, nt);
    k_scan3<<<nt, SCAN_TILE, 0, stream>>>(offs, tiles, NNODE, NEDGE);
    k_fill<<<(NEDGE + 255) / 256, 256, 0, stream>>>(srcp, dstp, offs, cursor, elist, slist, dlist, NEDGE);

    // edge logits for BOTH layers in one pass over ef
    k_weatt<<<1, 256, 0, stream>>>(eW1, ae1, webuf1);
    k_weatt<<<1, 256, 0, stream>>>(eW2, ae2, webuf2);
    k_elog_both<<<(NEDGE + EB - 1) / EB, EB, 0, stream>>>(ef, webuf1, webuf2, elog1, elog2, NEDGE);

    // ---- layer 1 ----
    k_gemm<<<dim3((NNODE + 63) / 64, 4), 256, 0, stream>>>(x, W1, hbuf, NNODE, FIN);
    k_avec<<<(NNODE + 3) / 4, 256, 0, stream>>>(hbuf, as1, ad1, asrc, adst, NNODE);
    k_edgep<<<(NEDGE + 255) / 256, 256, 0, stream>>>(slist, dlist, elist, elog1, asrc, adst, pbuf, NEDGE);
    k_pself<<<(NNODE + 3) / 4, 256, 0, stream>>>(elog1, offs, elist, asrc, adst, pself, NNODE);
    k_aggr<1><<<(NNODE + 3) / 4, 256, 0, stream>>>(hbuf, pbuf, pself, offs, slist, b1, x2buf, NNODE);

    // ---- layer 2 ----
    k_gemm<<<dim3((NNODE + 63) / 64, 4), 256, 0, stream>>>(x2buf, W2, hbuf, NNODE, HC);
    k_avec<<<(NNODE + 3) / 4, 256, 0, stream>>>(hbuf, as2, ad2, asrc, adst, NNODE);
    k_edgep<<<(NEDGE + 255) / 256, 256, 0, stream>>>(slist, dlist, elist, elog2, asrc, adst, pbuf, NEDGE);
    k_pself<<<(NNODE + 3) / 4, 256, 0, stream>>>(elog2, offs, elist, asrc, adst, pself, NNODE);
    k_aggr<2><<<(NNODE + 3) / 4, 256, 0, stream>>>(hbuf, pbuf, pself, offs, slist, b2, out, NNODE);
}

// Round 4
// 929.698 us; speedup vs baseline: 1.4932x; 1.0531x over previous
//
#include <hip/hip_runtime.h>
#include <hip/hip_fp16.h>
#include <math.h>

#define NNODE 50000
#define NEDGE 800000
#define FIN 128
#define EDIM 64
#define HC 256
#define NH 4
#define CC 64
#define SCAN_TILE 512
#define EB 128   // edges per block in k_elog_both

// ---------------- CSR build (dst -> incoming edge list) ----------------
__global__ void k_count(const int* __restrict__ dst, int* counts, int E) {
    int e = blockIdx.x * 256 + threadIdx.x;
    if (e < E) atomicAdd(&counts[dst[e]], 1);
}

__global__ void k_scan1(const int* __restrict__ counts, int* offs, int* tilesums, int N) {
    __shared__ int s[SCAN_TILE];
    int t = threadIdx.x;
    int i = blockIdx.x * SCAN_TILE + t;
    int v = (i < N) ? counts[i] : 0;
    s[t] = v;
    for (int off = 1; off < SCAN_TILE; off <<= 1) {
        __syncthreads();
        int x = (t >= off) ? s[t - off] : 0;
        __syncthreads();
        s[t] += x;
    }
    __syncthreads();
    if (i < N) offs[i] = s[t] - v;  // exclusive within tile
    if (t == SCAN_TILE - 1) tilesums[blockIdx.x] = s[t];
}

__global__ void k_scan2(int* tilesums, int nt) {
    if (threadIdx.x == 0) {
        int run = 0;
        for (int i = 0; i < nt; i++) { int v = tilesums[i]; tilesums[i] = run; run += v; }
    }
}

__global__ void k_scan3(int* offs, const int* __restrict__ tilesums, int N, int E) {
    int t = threadIdx.x;
    int i = blockIdx.x * SCAN_TILE + t;
    if (i < N) offs[i] += tilesums[blockIdx.x];
    if (i == 0) offs[N] = E;
}

__global__ void k_fill(const int* __restrict__ src, const int* __restrict__ dst,
                       const int* __restrict__ offs, int* cursor,
                       int* elist, int* slist, int* dlist, int E) {
    int e = blockIdx.x * 256 + threadIdx.x;
    if (e < E) {
        int d = dst[e];
        int pos = offs[d] + atomicAdd(&cursor[d], 1);
        elist[pos] = e;
        slist[pos] = src[e];
        dlist[pos] = d;
    }
}

__device__ inline float4 h4_to_f4(uint2 r) {
    float2 fa = __half22float2(*(__half2*)&r.x);
    float2 fb = __half22float2(*(__half2*)&r.y);
    return make_float4(fa.x, fa.y, fb.x, fb.y);
}

// ---------------- fp32 tiled GEMM: C[M,256] = A[M,K] @ B[K,256] (+ fp16 copy) ----------------
__global__ __launch_bounds__(256) void k_gemm(const float* __restrict__ A,
                                              const float* __restrict__ B,
                                              float* __restrict__ Cm,
                                              __half* __restrict__ Ch, int M, int K) {
    __shared__ float As[64][68];
    __shared__ float Bs[64][68];
    int tx = threadIdx.x & 15, ty = threadIdx.x >> 4;
    int row0 = blockIdx.x * 64, col0 = blockIdx.y * 64;
    float acc[4][4] = {};
    for (int k0 = 0; k0 < K; k0 += 64) {
        for (int i = 0; i < 4; i++) {
            int q = threadIdx.x + i * 256;       // float4 id 0..1023
            int m = q >> 4, k4 = (q & 15) << 2;
            float4 v = make_float4(0.f, 0.f, 0.f, 0.f);
            int gr = row0 + m;
            if (gr < M) v = *(const float4*)(A + (size_t)gr * K + k0 + k4);
            As[k4 + 0][m] = v.x; As[k4 + 1][m] = v.y;
            As[k4 + 2][m] = v.z; As[k4 + 3][m] = v.w;
            float4 wv = *(const float4*)(B + (size_t)(k0 + m) * HC + col0 + k4);
            *(float4*)&Bs[m][k4] = wv;
        }
        __syncthreads();
        for (int kk = 0; kk < 64; kk++) {
            float a[4], b[4];
            *(float4*)a = *(float4*)&As[kk][ty * 4];
            *(float4*)b = *(float4*)&Bs[kk][tx * 4];
            for (int i = 0; i < 4; i++)
                for (int j = 0; j < 4; j++) acc[i][j] += a[i] * b[j];
        }
        __syncthreads();
    }
    for (int i = 0; i < 4; i++) {
        int gr = row0 + ty * 4 + i;
        if (gr < M) {
            *(float4*)(Cm + (size_t)gr * HC + col0 + tx * 4) = *(float4*)acc[i];
            __half2 h01 = __floats2half2_rn(acc[i][0], acc[i][1]);
            __half2 h23 = __floats2half2_rn(acc[i][2], acc[i][3]);
            uint2 pk;
            pk.x = *(unsigned*)&h01;
            pk.y = *(unsigned*)&h23;
            ((uint2*)Ch)[((size_t)gr * HC + col0 + tx * 4) >> 2] = pk;
        }
    }
}

// ---------------- per-node attention coefficients a_src, a_dst ----------------
__global__ void k_avec(const float* __restrict__ h, const float* __restrict__ att_s,
                       const float* __restrict__ att_d, float* asrc, float* adst, int N) {
    int wave = threadIdx.x >> 6, lane = threadIdx.x & 63;
    int n = blockIdx.x * 4 + wave;
    if (n >= N) return;
    for (int hh = 0; hh < 4; hh++) {
        float hv = h[(size_t)n * HC + hh * 64 + lane];
        float vs = hv * att_s[hh * 64 + lane];
        float vd = hv * att_d[hh * 64 + lane];
        for (int m = 32; m >= 1; m >>= 1) {
            vs += __shfl_xor(vs, m, 64);
            vd += __shfl_xor(vd, m, 64);
        }
        if (lane == 0) { asrc[n * 4 + hh] = vs; adst[n * 4 + hh] = vd; }
    }
}

// ---------------- we_att[d,h] = sum_c edgeW[d, h*64+c] * att_e[h,c] ----------------
__global__ void k_weatt(const float* __restrict__ edgeW, const float* __restrict__ att_e,
                        float* we) {
    int t = threadIdx.x;
    int d = t >> 2, hh = t & 3;
    float s = 0.f;
    for (int c = 0; c < 64; c++) s += edgeW[d * HC + hh * 64 + c] * att_e[hh * 64 + c];
    we[d * 4 + hh] = s;
}

// ---------------- elog{1,2}[e,h] = edge_feat[e,:] . we{1,2}[:,h]  (both layers, one ef pass) ----
__global__ __launch_bounds__(128) void k_elog_both(const float* __restrict__ ef,
                                                   const float* __restrict__ we1,
                                                   const float* __restrict__ we2,
                                                   float* __restrict__ elog1,
                                                   float* __restrict__ elog2, int E) {
    __shared__ float sEf[EB][65];
    int t = threadIdx.x;
    int e0 = blockIdx.x * EB;
    for (int i = 0; i < 16; i++) {
        int q = t + i * 128;
        int le = q >> 4, c4 = (q & 15) << 2;
        int ge = e0 + le;
        float4 v = make_float4(0.f, 0.f, 0.f, 0.f);
        if (ge < E) v = *(const float4*)(ef + (size_t)ge * EDIM + c4);
        sEf[le][c4 + 0] = v.x; sEf[le][c4 + 1] = v.y;
        sEf[le][c4 + 2] = v.z; sEf[le][c4 + 3] = v.w;
    }
    __syncthreads();
    float a1[4] = {}, a2[4] = {};
#pragma unroll 8
    for (int c = 0; c < 64; c++) {
        float v = sEf[t][c];
        float4 w1 = *(const float4*)(we1 + c * 4);
        float4 w2 = *(const float4*)(we2 + c * 4);
        a1[0] += v * w1.x; a1[1] += v * w1.y; a1[2] += v * w1.z; a1[3] += v * w1.w;
        a2[0] += v * w2.x; a2[1] += v * w2.y; a2[2] += v * w2.z; a2[3] += v * w2.w;
    }
    int e = e0 + t;
    if (e < E) {
        ((float4*)elog1)[e] = make_float4(a1[0], a1[1], a1[2], a1[3]);
        ((float4*)elog2)[e] = make_float4(a2[0], a2[1], a2[2], a2[3]);
    }
}

// ---------------- per-edge attention numerator in CSR order ----------------
__global__ void k_edgep(const int* __restrict__ slist, const int* __restrict__ dlist,
                        const int* __restrict__ elist,
                        const float* __restrict__ elog, const float* __restrict__ asrc,
                        const float* __restrict__ adst, float* __restrict__ pcsr, int E) {
    int i = blockIdx.x * 256 + threadIdx.x;
    if (i >= E) return;
    float4 el = ((const float4*)elog)[elist[i]];
    float4 as = ((const float4*)asrc)[slist[i]];
    float4 ad = ((const float4*)adst)[dlist[i]];
    float4 o;
    float l;
    l = as.x + ad.x + el.x; l = l > 0.f ? l : 0.2f * l; o.x = expf(l);
    l = as.y + ad.y + el.y; l = l > 0.f ? l : 0.2f * l; o.y = expf(l);
    l = as.z + ad.z + el.z; l = l > 0.f ? l : 0.2f * l; o.z = expf(l);
    l = as.w + ad.w + el.w; l = l > 0.f ? l : 0.2f * l; o.w = expf(l);
    ((float4*)pcsr)[i] = o;
}

// ---------------- self-loop numerator pself (uses CSR segment sum of elog) ----------------
__global__ void k_pself(const float* __restrict__ elog, const int* __restrict__ offs,
                        const int* __restrict__ elist, const float* __restrict__ asrc,
                        const float* __restrict__ adst, float* __restrict__ pself, int N) {
    int wave = threadIdx.x >> 6, lane = threadIdx.x & 63;
    int n = blockIdx.x * 4 + wave;
    if (n >= N) return;
    int beg = offs[n], end = offs[n + 1];
    float s0 = 0.f, s1 = 0.f, s2 = 0.f, s3 = 0.f;
    for (int i = beg + lane; i < end; i += 64) {
        float4 el = ((const float4*)elog)[elist[i]];
        s0 += el.x; s1 += el.y; s2 += el.z; s3 += el.w;
    }
    for (int m = 32; m >= 1; m >>= 1) {
        s0 += __shfl_xor(s0, m, 64);
        s1 += __shfl_xor(s1, m, 64);
        s2 += __shfl_xor(s2, m, 64);
        s3 += __shfl_xor(s3, m, 64);
    }
    if (lane == 0) {
        float cnt = (float)(end - beg);
        if (cnt < 1.f) cnt = 1.f;
        float4 as = ((const float4*)asrc)[n];
        float4 ad = ((const float4*)adst)[n];
        float4 o;
        float l;
        l = as.x + ad.x + s0 / cnt; l = l > 0.f ? l : 0.2f * l; o.x = expf(l);
        l = as.y + ad.y + s1 / cnt; l = l > 0.f ? l : 0.2f * l; o.y = expf(l);
        l = as.z + ad.z + s2 / cnt; l = l > 0.f ? l : 0.2f * l; o.z = expf(l);
        l = as.w + ad.w + s3 / cnt; l = l > 0.f ? l : 0.2f * l; o.w = expf(l);
        ((float4*)pself)[n] = o;
    }
}

// ---------------- aggregation: wave/node, lane/(4 flat channels), fp16 gather ----------------
template <int LAYER>
__global__ __launch_bounds__(256) void k_aggr(const __half* __restrict__ hb,
                                              const float* __restrict__ pcsr,
                                              const float* __restrict__ pself,
                                              const int* __restrict__ offs,
                                              const int* __restrict__ slist,
                                              const float* __restrict__ bias,
                                              float* __restrict__ out, int N) {
    int wave = threadIdx.x >> 6, lane = threadIdx.x & 63;
    int n = blockIdx.x * 4 + wave;
    if (n >= N) return;
    int head = lane >> 4;
    const uint2* hf = (const uint2*)hb;     // 4 halves per entry, 64 entries per row
    const float4* pc = (const float4*)pcsr;
    int beg = offs[n], end = offs[n + 1];

    float4 ps4 = ((const float4*)pself)[n];
    float ps = head == 0 ? ps4.x : head == 1 ? ps4.y : head == 2 ? ps4.z : ps4.w;
    float4 hv = h4_to_f4(hf[(size_t)n * 64 + lane]);
    float denom = ps;
    float ax = ps * hv.x, ay = ps * hv.y, az = ps * hv.z, aw = ps * hv.w;

    int i = beg;
    for (; i + 8 <= end; i += 8) {
        int s[8];
        uint2 r[8];
        float4 p[8];
#pragma unroll
        for (int j = 0; j < 8; j++) s[j] = slist[i + j];
#pragma unroll
        for (int j = 0; j < 8; j++) r[j] = hf[(size_t)s[j] * 64 + lane];
#pragma unroll
        for (int j = 0; j < 8; j++) p[j] = pc[i + j];
#pragma unroll
        for (int j = 0; j < 8; j++) {
            float w = head == 0 ? p[j].x : head == 1 ? p[j].y : head == 2 ? p[j].z : p[j].w;
            float4 h4 = h4_to_f4(r[j]);
            denom += w;
            ax += w * h4.x; ay += w * h4.y; az += w * h4.z; aw += w * h4.w;
        }
    }
    for (; i < end; i++) {
        int s0 = slist[i];
        float4 p0 = pc[i];
        float4 h4 = h4_to_f4(hf[(size_t)s0 * 64 + lane]);
        float w0 = head == 0 ? p0.x : head == 1 ? p0.y : head == 2 ? p0.z : p0.w;
        denom += w0;
        ax += w0 * h4.x; ay += w0 * h4.y; az += w0 * h4.z; aw += w0 * h4.w;
    }
    float inv = 1.0f / (denom + 1e-16f);
    ax *= inv; ay *= inv; az *= inv; aw *= inv;

    if (LAYER == 1) {
        float4 bv = ((const float4*)bias)[lane];
        float4 o;
        float v;
        v = ax + bv.x; o.x = v > 0.f ? v : expf(v) - 1.0f;
        v = ay + bv.y; o.y = v > 0.f ? v : expf(v) - 1.0f;
        v = az + bv.z; o.z = v > 0.f ? v : expf(v) - 1.0f;
        v = aw + bv.w; o.w = v > 0.f ? v : expf(v) - 1.0f;
        ((float4*)(out + (size_t)n * HC))[lane] = o;
    } else {
        // mean over heads: reduce lanes {l, l^16, l^32, l^48}
        ax += __shfl_xor(ax, 16, 64); ax += __shfl_xor(ax, 32, 64);
        ay += __shfl_xor(ay, 16, 64); ay += __shfl_xor(ay, 32, 64);
        az += __shfl_xor(az, 16, 64); az += __shfl_xor(az, 32, 64);
        aw += __shfl_xor(aw, 16, 64); aw += __shfl_xor(aw, 32, 64);
        if (lane < 16) {
            float4 bv = ((const float4*)bias)[lane];
            float4 o;
            o.x = 0.25f * ax + bv.x;
            o.y = 0.25f * ay + bv.y;
            o.z = 0.25f * az + bv.z;
            o.w = 0.25f * aw + bv.w;
            ((float4*)(out + (size_t)n * CC))[lane] = o;
        }
    }
}

extern "C" void kernel_launch(void* const* d_in, const int* in_sizes, int n_in,
                              void* d_out, int out_size, void* d_ws, size_t ws_size,
                              hipStream_t stream) {
    const float* x   = (const float*)d_in[0];
    const float* ef  = (const float*)d_in[1];
    const int*   ei  = (const int*)d_in[2];
    const float* W1  = (const float*)d_in[3];
    const float* as1 = (const float*)d_in[4];
    const float* ad1 = (const float*)d_in[5];
    const float* ae1 = (const float*)d_in[6];
    const float* b1  = (const float*)d_in[7];
    const float* eW1 = (const float*)d_in[8];
    const float* W2  = (const float*)d_in[9];
    const float* as2 = (const float*)d_in[10];
    const float* ad2 = (const float*)d_in[11];
    const float* ae2 = (const float*)d_in[12];
    const float* b2  = (const float*)d_in[13];
    const float* eW2 = (const float*)d_in[14];
    float* out = (float*)d_out;
    const int* srcp = ei;
    const int* dstp = ei + NEDGE;

    char* w = (char*)d_ws;
    auto alloc = [&](size_t bytes) -> char* {
        char* r = w;
        w += (bytes + 255) / 256 * 256;
        return r;
    };
    float* hbuf   = (float*)alloc((size_t)NNODE * HC * 4);
    __half* hb16  = (__half*)alloc((size_t)NNODE * HC * 2);
    float* x2buf  = (float*)alloc((size_t)NNODE * HC * 4);
    float* elog1  = (float*)alloc((size_t)NEDGE * 4 * 4);
    float* elog2  = (float*)alloc((size_t)NEDGE * 4 * 4);
    float* pbuf   = (float*)alloc((size_t)NEDGE * 4 * 4);
    float* asrc   = (float*)alloc((size_t)NNODE * 4 * 4);
    float* adst   = (float*)alloc((size_t)NNODE * 4 * 4);
    float* pself  = (float*)alloc((size_t)NNODE * 4 * 4);
    float* webuf1 = (float*)alloc(64 * 4 * 4);
    float* webuf2 = (float*)alloc(64 * 4 * 4);
    int* counts  = (int*)alloc((size_t)NNODE * 4);
    int* offs    = (int*)alloc((size_t)(NNODE + 1) * 4);
    int* tiles   = (int*)alloc(1024 * 4);
    int* cursor  = (int*)alloc((size_t)NNODE * 4);
    int* elist   = (int*)alloc((size_t)NEDGE * 4);
    int* slist   = (int*)alloc((size_t)NEDGE * 4);
    int* dlist   = (int*)alloc((size_t)NEDGE * 4);

    hipMemsetAsync(counts, 0, (size_t)NNODE * 4, stream);
    hipMemsetAsync(cursor, 0, (size_t)NNODE * 4, stream);

    // CSR build (shared by both layers)
    k_count<<<(NEDGE + 255) / 256, 256, 0, stream>>>(dstp, counts, NEDGE);
    int nt = (NNODE + SCAN_TILE - 1) / SCAN_TILE;
    k_scan1<<<nt, SCAN_TILE, 0, stream>>>(counts, offs, tiles, NNODE);
    k_scan2<<<1, 64, 0, stream>>>(tiles, nt);
    k_scan3<<<nt, SCAN_TILE, 0, stream>>>(offs, tiles, NNODE, NEDGE);
    k_fill<<<(NEDGE + 255) / 256, 256, 0, stream>>>(srcp, dstp, offs, cursor, elist, slist, dlist, NEDGE);

    // edge logits for BOTH layers in one pass over ef
    k_weatt<<<1, 256, 0, stream>>>(eW1, ae1, webuf1);
    k_weatt<<<1, 256, 0, stream>>>(eW2, ae2, webuf2);
    k_elog_both<<<(NEDGE + EB - 1) / EB, EB, 0, stream>>>(ef, webuf1, webuf2, elog1, elog2, NEDGE);

    // ---- layer 1 ----
    k_gemm<<<dim3((NNODE + 63) / 64, 4), 256, 0, stream>>>(x, W1, hbuf, hb16, NNODE, FIN);
    k_avec<<<(NNODE + 3) / 4, 256, 0, stream>>>(hbuf, as1, ad1, asrc, adst, NNODE);
    k_edgep<<<(NEDGE + 255) / 256, 256, 0, stream>>>(slist, dlist, elist, elog1, asrc, adst, pbuf, NEDGE);
    k_pself<<<(NNODE + 3) / 4, 256, 0, stream>>>(elog1, offs, elist, asrc, adst, pself, NNODE);
    k_aggr<1><<<(NNODE + 3) / 4, 256, 0, stream>>>(hb16, pbuf, pself, offs, slist, b1, x2buf, NNODE);

    // ---- layer 2 ----
    k_gemm<<<dim3((NNODE + 63) / 64, 4), 256, 0, stream>>>(x2buf, W2, hbuf, hb16, NNODE, HC);
    k_avec<<<(NNODE + 3) / 4, 256, 0, stream>>>(hbuf, as2, ad2, asrc, adst, NNODE);
    k_edgep<<<(NEDGE + 255) / 256, 256, 0, stream>>>(slist, dlist, elist, elog2, asrc, adst, pbuf, NEDGE);
    k_pself<<<(NNODE + 3) / 4, 256, 0, stream>>>(elog2, offs, elist, asrc, adst, pself, NNODE);
    k_aggr<2><<<(NNODE + 3) / 4, 256, 0, stream>>>(hb16, pbuf, pself, offs, slist, b2, out, NNODE);
}

// Round 5
// 897.777 us; speedup vs baseline: 1.5463x; 1.0356x over previous
//
#include <hip/hip_runtime.h>
#include <hip/hip_fp16.h>
#include <math.h>

#define NNODE 50000
#define NEDGE 800000
#define FIN 128
#define EDIM 64
#define HC 256
#define NH 4
#define CC 64
#define SCAN_TILE 512
#define EB 128   // edges per block in k_elog_both

typedef _Float16 half8v __attribute__((ext_vector_type(8)));
typedef _Float16 half4v __attribute__((ext_vector_type(4)));
typedef float floatx4 __attribute__((ext_vector_type(4)));

// ---------------- CSR build (dst -> incoming edge list) ----------------
__global__ void k_count(const int* __restrict__ dst, int* counts, int E) {
    int e = blockIdx.x * 256 + threadIdx.x;
    if (e < E) atomicAdd(&counts[dst[e]], 1);
}

__global__ void k_scan1(const int* __restrict__ counts, int* offs, int* tilesums, int N) {
    __shared__ int s[SCAN_TILE];
    int t = threadIdx.x;
    int i = blockIdx.x * SCAN_TILE + t;
    int v = (i < N) ? counts[i] : 0;
    s[t] = v;
    for (int off = 1; off < SCAN_TILE; off <<= 1) {
        __syncthreads();
        int x = (t >= off) ? s[t - off] : 0;
        __syncthreads();
        s[t] += x;
    }
    __syncthreads();
    if (i < N) offs[i] = s[t] - v;  // exclusive within tile
    if (t == SCAN_TILE - 1) tilesums[blockIdx.x] = s[t];
}

__global__ void k_scan2(int* tilesums, int nt) {
    if (threadIdx.x == 0) {
        int run = 0;
        for (int i = 0; i < nt; i++) { int v = tilesums[i]; tilesums[i] = run; run += v; }
    }
}

__global__ void k_scan3(int* offs, const int* __restrict__ tilesums, int N, int E) {
    int t = threadIdx.x;
    int i = blockIdx.x * SCAN_TILE + t;
    if (i < N) offs[i] += tilesums[blockIdx.x];
    if (i == 0) offs[N] = E;
}

__global__ void k_fill(const int* __restrict__ src, const int* __restrict__ dst,
                       const int* __restrict__ offs, int* cursor,
                       int* elist, int* slist, int* dlist, int E) {
    int e = blockIdx.x * 256 + threadIdx.x;
    if (e < E) {
        int d = dst[e];
        int pos = offs[d] + atomicAdd(&cursor[d], 1);
        elist[pos] = e;
        slist[pos] = src[e];
        dlist[pos] = d;
    }
}

__device__ inline float4 h4_to_f4(uint2 r) {
    float2 fa = __half22float2(*(__half2*)&r.x);
    float2 fb = __half22float2(*(__half2*)&r.y);
    return make_float4(fa.x, fa.y, fb.x, fb.y);
}

// ---------------- casts ----------------
__global__ void k_cast_x(const float* __restrict__ x, _Float16* __restrict__ x16, int n4) {
    int i = blockIdx.x * 256 + threadIdx.x;
    if (i >= n4) return;
    float4 v = ((const float4*)x)[i];
    half4v o;
    o[0] = (_Float16)v.x; o[1] = (_Float16)v.y; o[2] = (_Float16)v.z; o[3] = (_Float16)v.w;
    ((half4v*)x16)[i] = o;
}

// W[K,256] fp32 -> Wt[256,K] fp16 (transpose); grid=K, block=256
__global__ void k_castW(const float* __restrict__ W, _Float16* __restrict__ Wt, int K) {
    int k = blockIdx.x, n = threadIdx.x;
    Wt[(size_t)n * K + k] = (_Float16)W[(size_t)k * HC + n];
}

// ---------------- fp16 MFMA GEMM: H16[M,256] = A16[M,K] @ Wt16^T ----------------
// wave = 16 rows x 256 cols (16 acc tiles), block = 4 waves = 64 rows
__global__ __launch_bounds__(256) void k_gemm_mfma(const _Float16* __restrict__ A16,
                                                   const _Float16* __restrict__ Wt16,
                                                   _Float16* __restrict__ H16,
                                                   int M, int K) {
    int wave = threadIdx.x >> 6, lane = threadIdx.x & 63;
    int quad = lane >> 4, l16 = lane & 15;
    int row = blockIdx.x * 64 + wave * 16 + l16;     // A-frag row
    bool rok = row < M;
    floatx4 acc[16];
#pragma unroll
    for (int i = 0; i < 16; i++) acc[i] = (floatx4)(0.0f);
    int nk = K >> 5;
    const _Float16* ap = A16 + (size_t)row * K + quad * 8;
    for (int kk = 0; kk < nk; kk++) {
        half8v a = {};
        if (rok) a = *(const half8v*)(ap + kk * 32);
#pragma unroll
        for (int nt = 0; nt < 16; nt++) {
            half8v b = *(const half8v*)(Wt16 + (size_t)(nt * 16 + l16) * K + kk * 32 + quad * 8);
            acc[nt] = __builtin_amdgcn_mfma_f32_16x16x32_f16(a, b, acc[nt], 0, 0, 0);
        }
    }
    // D layout: col = nt*16 + l16, row-in-tile = quad*4 + r
    int orow0 = blockIdx.x * 64 + wave * 16 + quad * 4;
#pragma unroll
    for (int r = 0; r < 4; r++) {
        int orow = orow0 + r;
        if (orow < M) {
#pragma unroll
            for (int nt = 0; nt < 16; nt++)
                H16[(size_t)orow * HC + nt * 16 + l16] = (_Float16)acc[nt][r];
        }
    }
}

// ---------------- per-node attention coefficients a_src, a_dst (fp16 h) ----------------
__global__ void k_avec(const _Float16* __restrict__ h, const float* __restrict__ att_s,
                       const float* __restrict__ att_d, float* asrc, float* adst, int N) {
    int wave = threadIdx.x >> 6, lane = threadIdx.x & 63;
    int n = blockIdx.x * 4 + wave;
    if (n >= N) return;
    for (int hh = 0; hh < 4; hh++) {
        float hv = (float)h[(size_t)n * HC + hh * 64 + lane];
        float vs = hv * att_s[hh * 64 + lane];
        float vd = hv * att_d[hh * 64 + lane];
        for (int m = 32; m >= 1; m >>= 1) {
            vs += __shfl_xor(vs, m, 64);
            vd += __shfl_xor(vd, m, 64);
        }
        if (lane == 0) { asrc[n * 4 + hh] = vs; adst[n * 4 + hh] = vd; }
    }
}

// ---------------- we_att[d,h] = sum_c edgeW[d, h*64+c] * att_e[h,c] ----------------
__global__ void k_weatt(const float* __restrict__ edgeW, const float* __restrict__ att_e,
                        float* we) {
    int t = threadIdx.x;
    int d = t >> 2, hh = t & 3;
    float s = 0.f;
    for (int c = 0; c < 64; c++) s += edgeW[d * HC + hh * 64 + c] * att_e[hh * 64 + c];
    we[d * 4 + hh] = s;
}

// ---------------- elog{1,2}[e,h] = edge_feat[e,:] . we{1,2}[:,h]  (both layers, one ef pass) ----
__global__ __launch_bounds__(128) void k_elog_both(const float* __restrict__ ef,
                                                   const float* __restrict__ we1,
                                                   const float* __restrict__ we2,
                                                   float* __restrict__ elog1,
                                                   float* __restrict__ elog2, int E) {
    __shared__ float sEf[EB][65];
    int t = threadIdx.x;
    int e0 = blockIdx.x * EB;
    for (int i = 0; i < 16; i++) {
        int q = t + i * 128;
        int le = q >> 4, c4 = (q & 15) << 2;
        int ge = e0 + le;
        float4 v = make_float4(0.f, 0.f, 0.f, 0.f);
        if (ge < E) v = *(const float4*)(ef + (size_t)ge * EDIM + c4);
        sEf[le][c4 + 0] = v.x; sEf[le][c4 + 1] = v.y;
        sEf[le][c4 + 2] = v.z; sEf[le][c4 + 3] = v.w;
    }
    __syncthreads();
    float a1[4] = {}, a2[4] = {};
#pragma unroll 8
    for (int c = 0; c < 64; c++) {
        float v = sEf[t][c];
        float4 w1 = *(const float4*)(we1 + c * 4);
        float4 w2 = *(const float4*)(we2 + c * 4);
        a1[0] += v * w1.x; a1[1] += v * w1.y; a1[2] += v * w1.z; a1[3] += v * w1.w;
        a2[0] += v * w2.x; a2[1] += v * w2.y; a2[2] += v * w2.z; a2[3] += v * w2.w;
    }
    int e = e0 + t;
    if (e < E) {
        ((float4*)elog1)[e] = make_float4(a1[0], a1[1], a1[2], a1[3]);
        ((float4*)elog2)[e] = make_float4(a2[0], a2[1], a2[2], a2[3]);
    }
}

// ---------------- per-edge attention numerator in CSR order ----------------
__global__ void k_edgep(const int* __restrict__ slist, const int* __restrict__ dlist,
                        const int* __restrict__ elist,
                        const float* __restrict__ elog, const float* __restrict__ asrc,
                        const float* __restrict__ adst, float* __restrict__ pcsr, int E) {
    int i = blockIdx.x * 256 + threadIdx.x;
    if (i >= E) return;
    float4 el = ((const float4*)elog)[elist[i]];
    float4 as = ((const float4*)asrc)[slist[i]];
    float4 ad = ((const float4*)adst)[dlist[i]];
    float4 o;
    float l;
    l = as.x + ad.x + el.x; l = l > 0.f ? l : 0.2f * l; o.x = expf(l);
    l = as.y + ad.y + el.y; l = l > 0.f ? l : 0.2f * l; o.y = expf(l);
    l = as.z + ad.z + el.z; l = l > 0.f ? l : 0.2f * l; o.z = expf(l);
    l = as.w + ad.w + el.w; l = l > 0.f ? l : 0.2f * l; o.w = expf(l);
    ((float4*)pcsr)[i] = o;
}

// ---------------- self-loop numerator pself (uses CSR segment sum of elog) ----------------
__global__ void k_pself(const float* __restrict__ elog, const int* __restrict__ offs,
                        const int* __restrict__ elist, const float* __restrict__ asrc,
                        const float* __restrict__ adst, float* __restrict__ pself, int N) {
    int wave = threadIdx.x >> 6, lane = threadIdx.x & 63;
    int n = blockIdx.x * 4 + wave;
    if (n >= N) return;
    int beg = offs[n], end = offs[n + 1];
    float s0 = 0.f, s1 = 0.f, s2 = 0.f, s3 = 0.f;
    for (int i = beg + lane; i < end; i += 64) {
        float4 el = ((const float4*)elog)[elist[i]];
        s0 += el.x; s1 += el.y; s2 += el.z; s3 += el.w;
    }
    for (int m = 32; m >= 1; m >>= 1) {
        s0 += __shfl_xor(s0, m, 64);
        s1 += __shfl_xor(s1, m, 64);
        s2 += __shfl_xor(s2, m, 64);
        s3 += __shfl_xor(s3, m, 64);
    }
    if (lane == 0) {
        float cnt = (float)(end - beg);
        if (cnt < 1.f) cnt = 1.f;
        float4 as = ((const float4*)asrc)[n];
        float4 ad = ((const float4*)adst)[n];
        float4 o;
        float l;
        l = as.x + ad.x + s0 / cnt; l = l > 0.f ? l : 0.2f * l; o.x = expf(l);
        l = as.y + ad.y + s1 / cnt; l = l > 0.f ? l : 0.2f * l; o.y = expf(l);
        l = as.z + ad.z + s2 / cnt; l = l > 0.f ? l : 0.2f * l; o.z = expf(l);
        l = as.w + ad.w + s3 / cnt; l = l > 0.f ? l : 0.2f * l; o.w = expf(l);
        ((float4*)pself)[n] = o;
    }
}

// ---------------- aggregation: wave/node, lane/(4 flat channels), fp16 gather ----------------
// LAYER 1 writes fp16 x2 (GEMM input); LAYER 2 writes fp32 final out.
template <int LAYER>
__global__ __launch_bounds__(256) void k_aggr(const _Float16* __restrict__ hb,
                                              const float* __restrict__ pcsr,
                                              const float* __restrict__ pself,
                                              const int* __restrict__ offs,
                                              const int* __restrict__ slist,
                                              const float* __restrict__ bias,
                                              _Float16* __restrict__ out16,
                                              float* __restrict__ out32, int N) {
    int wave = threadIdx.x >> 6, lane = threadIdx.x & 63;
    int n = blockIdx.x * 4 + wave;
    if (n >= N) return;
    int head = lane >> 4;
    const uint2* hf = (const uint2*)hb;     // 4 halves per entry, 64 entries per row
    const float4* pc = (const float4*)pcsr;
    int beg = offs[n], end = offs[n + 1];

    float4 ps4 = ((const float4*)pself)[n];
    float ps = head == 0 ? ps4.x : head == 1 ? ps4.y : head == 2 ? ps4.z : ps4.w;
    float4 hv = h4_to_f4(hf[(size_t)n * 64 + lane]);
    float denom = ps;
    float ax = ps * hv.x, ay = ps * hv.y, az = ps * hv.z, aw = ps * hv.w;

    int i = beg;
    for (; i + 8 <= end; i += 8) {
        int s[8];
        uint2 r[8];
        float4 p[8];
#pragma unroll
        for (int j = 0; j < 8; j++) s[j] = slist[i + j];
#pragma unroll
        for (int j = 0; j < 8; j++) r[j] = hf[(size_t)s[j] * 64 + lane];
#pragma unroll
        for (int j = 0; j < 8; j++) p[j] = pc[i + j];
#pragma unroll
        for (int j = 0; j < 8; j++) {
            float w = head == 0 ? p[j].x : head == 1 ? p[j].y : head == 2 ? p[j].z : p[j].w;
            float4 h4 = h4_to_f4(r[j]);
            denom += w;
            ax += w * h4.x; ay += w * h4.y; az += w * h4.z; aw += w * h4.w;
        }
    }
    for (; i < end; i++) {
        int s0 = slist[i];
        float4 p0 = pc[i];
        float4 h4 = h4_to_f4(hf[(size_t)s0 * 64 + lane]);
        float w0 = head == 0 ? p0.x : head == 1 ? p0.y : head == 2 ? p0.z : p0.w;
        denom += w0;
        ax += w0 * h4.x; ay += w0 * h4.y; az += w0 * h4.z; aw += w0 * h4.w;
    }
    float inv = 1.0f / (denom + 1e-16f);
    ax *= inv; ay *= inv; az *= inv; aw *= inv;

    if (LAYER == 1) {
        float4 bv = ((const float4*)bias)[lane];
        half4v o;
        float v;
        v = ax + bv.x; o[0] = (_Float16)(v > 0.f ? v : expf(v) - 1.0f);
        v = ay + bv.y; o[1] = (_Float16)(v > 0.f ? v : expf(v) - 1.0f);
        v = az + bv.z; o[2] = (_Float16)(v > 0.f ? v : expf(v) - 1.0f);
        v = aw + bv.w; o[3] = (_Float16)(v > 0.f ? v : expf(v) - 1.0f);
        ((half4v*)(out16 + (size_t)n * HC))[lane] = o;
    } else {
        // mean over heads: reduce lanes {l, l^16, l^32, l^48}
        ax += __shfl_xor(ax, 16, 64); ax += __shfl_xor(ax, 32, 64);
        ay += __shfl_xor(ay, 16, 64); ay += __shfl_xor(ay, 32, 64);
        az += __shfl_xor(az, 16, 64); az += __shfl_xor(az, 32, 64);
        aw += __shfl_xor(aw, 16, 64); aw += __shfl_xor(aw, 32, 64);
        if (lane < 16) {
            float4 bv = ((const float4*)bias)[lane];
            float4 o;
            o.x = 0.25f * ax + bv.x;
            o.y = 0.25f * ay + bv.y;
            o.z = 0.25f * az + bv.z;
            o.w = 0.25f * aw + bv.w;
            ((float4*)(out32 + (size_t)n * CC))[lane] = o;
        }
    }
}

extern "C" void kernel_launch(void* const* d_in, const int* in_sizes, int n_in,
                              void* d_out, int out_size, void* d_ws, size_t ws_size,
                              hipStream_t stream) {
    const float* x   = (const float*)d_in[0];
    const float* ef  = (const float*)d_in[1];
    const int*   ei  = (const int*)d_in[2];
    const float* W1  = (const float*)d_in[3];
    const float* as1 = (const float*)d_in[4];
    const float* ad1 = (const float*)d_in[5];
    const float* ae1 = (const float*)d_in[6];
    const float* b1  = (const float*)d_in[7];
    const float* eW1 = (const float*)d_in[8];
    const float* W2  = (const float*)d_in[9];
    const float* as2 = (const float*)d_in[10];
    const float* ad2 = (const float*)d_in[11];
    const float* ae2 = (const float*)d_in[12];
    const float* b2  = (const float*)d_in[13];
    const float* eW2 = (const float*)d_in[14];
    float* out = (float*)d_out;
    const int* srcp = ei;
    const int* dstp = ei + NEDGE;

    char* w = (char*)d_ws;
    auto alloc = [&](size_t bytes) -> char* {
        char* r = w;
        w += (bytes + 255) / 256 * 256;
        return r;
    };
    _Float16* hb16  = (_Float16*)alloc((size_t)NNODE * HC * 2);   // h (fp16, both layers)
    _Float16* x16   = (_Float16*)alloc((size_t)NNODE * FIN * 2);  // layer-1 GEMM input
    _Float16* x216  = (_Float16*)alloc((size_t)NNODE * HC * 2);   // layer-2 GEMM input
    _Float16* wt1   = (_Float16*)alloc((size_t)HC * FIN * 2);     // W1^T fp16
    _Float16* wt2   = (_Float16*)alloc((size_t)HC * HC * 2);      // W2^T fp16
    float* elog1  = (float*)alloc((size_t)NEDGE * 4 * 4);
    float* elog2  = (float*)alloc((size_t)NEDGE * 4 * 4);
    float* pbuf   = (float*)alloc((size_t)NEDGE * 4 * 4);
    float* asrc   = (float*)alloc((size_t)NNODE * 4 * 4);
    float* adst   = (float*)alloc((size_t)NNODE * 4 * 4);
    float* pself  = (float*)alloc((size_t)NNODE * 4 * 4);
    float* webuf1 = (float*)alloc(64 * 4 * 4);
    float* webuf2 = (float*)alloc(64 * 4 * 4);
    int* counts  = (int*)alloc((size_t)NNODE * 4);
    int* offs    = (int*)alloc((size_t)(NNODE + 1) * 4);
    int* tiles   = (int*)alloc(1024 * 4);
    int* cursor  = (int*)alloc((size_t)NNODE * 4);
    int* elist   = (int*)alloc((size_t)NEDGE * 4);
    int* slist   = (int*)alloc((size_t)NEDGE * 4);
    int* dlist   = (int*)alloc((size_t)NEDGE * 4);

    hipMemsetAsync(counts, 0, (size_t)NNODE * 4, stream);
    hipMemsetAsync(cursor, 0, (size_t)NNODE * 4, stream);

    // CSR build (shared by both layers)
    k_count<<<(NEDGE + 255) / 256, 256, 0, stream>>>(dstp, counts, NEDGE);
    int nt = (NNODE + SCAN_TILE - 1) / SCAN_TILE;
    k_scan1<<<nt, SCAN_TILE, 0, stream>>>(counts, offs, tiles, NNODE);
    k_scan2<<<1, 64, 0, stream>>>(tiles, nt);
    k_scan3<<<nt, SCAN_TILE, 0, stream>>>(offs, tiles, NNODE, NEDGE);
    k_fill<<<(NEDGE + 255) / 256, 256, 0, stream>>>(srcp, dstp, offs, cursor, elist, slist, dlist, NEDGE);

    // fp16 conversions
    k_cast_x<<<(NNODE * FIN / 4 + 255) / 256, 256, 0, stream>>>(x, x16, NNODE * FIN / 4);
    k_castW<<<FIN, 256, 0, stream>>>(W1, wt1, FIN);
    k_castW<<<HC, 256, 0, stream>>>(W2, wt2, HC);

    // edge logits for BOTH layers in one pass over ef
    k_weatt<<<1, 256, 0, stream>>>(eW1, ae1, webuf1);
    k_weatt<<<1, 256, 0, stream>>>(eW2, ae2, webuf2);
    k_elog_both<<<(NEDGE + EB - 1) / EB, EB, 0, stream>>>(ef, webuf1, webuf2, elog1, elog2, NEDGE);

    // ---- layer 1 ----
    k_gemm_mfma<<<(NNODE + 63) / 64, 256, 0, stream>>>(x16, wt1, hb16, NNODE, FIN);
    k_avec<<<(NNODE + 3) / 4, 256, 0, stream>>>(hb16, as1, ad1, asrc, adst, NNODE);
    k_edgep<<<(NEDGE + 255) / 256, 256, 0, stream>>>(slist, dlist, elist, elog1, asrc, adst, pbuf, NEDGE);
    k_pself<<<(NNODE + 3) / 4, 256, 0, stream>>>(elog1, offs, elist, asrc, adst, pself, NNODE);
    k_aggr<1><<<(NNODE + 3) / 4, 256, 0, stream>>>(hb16, pbuf, pself, offs, slist, b1, x216, nullptr, NNODE);

    // ---- layer 2 ----
    k_gemm_mfma<<<(NNODE + 63) / 64, 256, 0, stream>>>(x216, wt2, hb16, NNODE, HC);
    k_avec<<<(NNODE + 3) / 4, 256, 0, stream>>>(hb16, as2, ad2, asrc, adst, NNODE);
    k_edgep<<<(NEDGE + 255) / 256, 256, 0, stream>>>(slist, dlist, elist, elog2, asrc, adst, pbuf, NEDGE);
    k_pself<<<(NNODE + 3) / 4, 256, 0, stream>>>(elog2, offs, elist, asrc, adst, pself, NNODE);
    k_aggr<2><<<(NNODE + 3) / 4, 256, 0, stream>>>(hb16, pbuf, pself, offs, slist, b2, nullptr, out, NNODE);
}